// Round 12
// baseline (194.339 us; speedup 1.0000x reference)
//
#include <hip/hip_runtime.h>
#include <math.h>

// B=4, C=256, H=W=64, G=4, Cg=64, P=9. x [B,HW,C] is NHWC already.
// Convs via implicit-GEMM MFMA (bf16 2-term split: hi*hi + hi*lo + lo*hi).
// Chunked SPLIT-ARRAY layout: activations [ch][b][SLAB px][32] hi/lo arrays.
// R17/R18: 3-tap LDS stages + px-split MT=2 (190us). R19: oc-split, direct
// m1 write, no atomics/finalize (182us).
// R20: conv3 roles MERGED back to one NT=4 role (m1 = 64 oc exactly):
//   R19's 2 oc-roles each staged the SAME A rows -> 2x A global reads + 2x A
//   LDS writes, and NT=2's read:MFMA ratio (24 FLOP/B) vs NT=4 (32 FLOP/B).
//   convA block-stages 9216 -> 6144 (-33%). Balance: 128 conv3 x 24 stages =
//   512 conv1 x 6 stages; conv3 dispatched first (low blockIdx).
//   convB keeps {48,32} oc-split (there it buys block-count balance).

#define SLAB 4369           // padded px per (ch,b) slab (4356 used + 13 pad)
#define AGAP 1056           // ushorts between arrays
#define APXS 40             // LDS padded px/oc stride in ushorts (80B)
#define AROW (66*APXS)      // 2640 ushorts per LDS A row

typedef __attribute__((ext_vector_type(8))) short short8;
typedef __attribute__((ext_vector_type(4))) float floatx4;

__device__ __forceinline__ unsigned short f2bf(float f) {
    unsigned u = __float_as_uint(f);
    u = (u + 0x7FFFu + ((u >> 16) & 1u)) >> 16;
    return (unsigned short)u;
}
__device__ __forceinline__ float bf2f(unsigned short h) {
    return __uint_as_float(((unsigned)h) << 16);
}
__device__ __forceinline__ void split2(float v, unsigned short* hi, unsigned short* lo) {
    unsigned short h = f2bf(v);
    *hi = h;
    *lo = f2bf(v - bf2f(h));
}
__device__ __forceinline__ float gelu_exact(float v) {
    return 0.5f * v * (1.0f + erff(v * 0.70710678118654752f));
}

// ---------------- LDS-staged MFMA implicit-GEMM conv core (3-tap stages) -----
// Global activations: [ch][b][SLAB px][32] ushort (hi/lo). px = y*66+x, padded.
// Global weights: [ch][tap][OCW][32] ushort (hi/lo); role reads cols
// oc0..oc0+NT*16 of each tap row (strided per-tap staging).
// Block = 4 waves, MT=2: wave = 32 px (half row); block = 128 px = 2 rows.
// Stage = one (ch, kh): A = 2 rows at y0+kh; B = 3 taps x NT*16 oc.
// NSTG = NC*3 stages. Per stage: [issue s+1] -> 3x(ds_read + MFMA) -> sync ->
// [write s+1] -> sync.
// A frag: m=l16 -> pixel, k=quad*8+j -> ic. B frag: n=l16 -> oc.
// C/D: col(oc)=lane&15, row(pixel)=quad*4+reg.
// ACT: 0 none, 1 gelu. OUTMODE: 1 split-bf16 out (bias+act) at column oc0+oc;
// 3 fp32 plain store, row stride OSTRF, column oc0+oc.
template<int NC, int MT, int NT, int OCW, int OSTRF, int ACT, int OUTMODE>
__device__ __forceinline__ void conv_core_lds(
    unsigned short* lds,
    const unsigned short* __restrict__ ah, const unsigned short* __restrict__ al,
    int aC0,
    const unsigned short* __restrict__ wh, const unsigned short* __restrict__ wl,
    int wC0,
    const float* __restrict__ bias,
    int b, int mblock,
    unsigned short* __restrict__ oh, unsigned short* __restrict__ ol,
    int oC0,
    float* __restrict__ pf,
    int oc0)
{
    const int NSTG = NC * 3;
    const int AHALF_ = MT * AROW;
    const int AU = MT * 66 * 4;          // 16B units per A half
    const int KA = (AU + 255) / 256;
    const int BHALF_ = 3 * NT * 16 * APXS;
    const int UB1 = NT * 64;             // 16B units per tap per half
    const int BU = 3 * UB1;
    const int KB = (BU + 255) / 256;

    unsigned short* Ahl = lds;
    unsigned short* All = lds + AHALF_;
    unsigned short* Bhl = lds + 2 * AHALF_;
    unsigned short* Bll = Bhl + BHALF_;

    int tid = (int)threadIdx.x;
    int wave = tid >> 6;
    int lane = tid & 63;
    int quad = lane >> 4;
    int l16 = lane & 15;

    int pix0 = (mblock * 4 + wave) * (MT * 16);
    int y0 = mblock * MT;                       // block's first image row
    int lr = wave >> 1;                         // wave's local row (MT=2)
    int xb_ = (wave & 1) * 32;

    floatx4 acc[MT][NT];
#pragma unroll
    for (int nt = 0; nt < NT; nt++) {
        float bv = (OUTMODE == 1) ? bias[nt * 16 + l16] : 0.f;
#pragma unroll
        for (int mt = 0; mt < MT; mt++) { floatx4 v = {bv, bv, bv, bv}; acc[mt][nt] = v; }
    }

    short8 ARh[KA], ARl[KA], BRh[KB], BRl[KB];

    auto issueAB = [&](int s) {
        int ch = s / 3;
        int kh = s % 3;
        size_t ga = ((size_t)((aC0 + ch) * 4 + b) * SLAB + (size_t)(y0 + kh) * 66) * 32;
#pragma unroll
        for (int k = 0; k < KA; k++) {
            int u = k * 256 + tid;
            if (u < AU) {
                ARh[k] = *(const short8*)(ah + ga + (size_t)u * 8);
                ARl[k] = *(const short8*)(al + ga + (size_t)u * 8);
            }
        }
        size_t gb = (((size_t)(wC0 + ch) * 9 + kh * 3) * OCW + oc0) * 32;
#pragma unroll
        for (int k = 0; k < KB; k++) {
            int u = k * 256 + tid;
            if (u < BU) {
                int tp = u / UB1;
                int r = u - tp * UB1;
                size_t src = gb + (size_t)tp * OCW * 32 + (size_t)r * 8;
                BRh[k] = *(const short8*)(wh + src);
                BRl[k] = *(const short8*)(wl + src);
            }
        }
    };
    auto writeAB = [&]() {
#pragma unroll
        for (int k = 0; k < KA; k++) {
            int u = k * 256 + tid;
            if (u < AU) {
                int px = u >> 2, j = u & 3;
                int row = px / 66, col = px - row * 66;
                int dst = row * AROW + col * APXS + j * 8;
                *(short8*)(Ahl + dst) = ARh[k];
                *(short8*)(All + dst) = ARl[k];
            }
        }
#pragma unroll
        for (int k = 0; k < KB; k++) {
            int u = k * 256 + tid;
            if (u < BU) {
                int tp = u / UB1;
                int r = u - tp * UB1;
                int dst = tp * (NT * 16 * APXS) + (r >> 2) * APXS + (r & 3) * 8;
                *(short8*)(Bhl + dst) = BRh[k];
                *(short8*)(Bll + dst) = BRl[k];
            }
        }
    };

    issueAB(0);
    writeAB();
    __syncthreads();

#pragma unroll 1
    for (int s = 0; s < NSTG; s++) {
        if (s + 1 < NSTG) {
            issueAB(s + 1);                      // issue-early: in flight under MFMA
            __builtin_amdgcn_sched_barrier(0);
        }
#pragma unroll
        for (int kw = 0; kw < 3; kw++) {
            short8 Afh[MT], Afl[MT], Bfh[NT], Bfl[NT];
#pragma unroll
            for (int mt = 0; mt < MT; mt++) {
                int aoff = lr * AROW + (xb_ + kw + l16 + mt * 16) * APXS + quad * 8;
                Afh[mt] = *(const short8*)(Ahl + aoff);
                Afl[mt] = *(const short8*)(All + aoff);
            }
#pragma unroll
            for (int nt = 0; nt < NT; nt++) {
                int boff = kw * (NT * 16 * APXS) + (nt * 16 + l16) * APXS + quad * 8;
                Bfh[nt] = *(const short8*)(Bhl + boff);
                Bfl[nt] = *(const short8*)(Bll + boff);
            }
            __builtin_amdgcn_s_setprio(1);
#pragma unroll
            for (int nt = 0; nt < NT; nt++) {
#pragma unroll
                for (int mt = 0; mt < MT; mt++) {
                    acc[mt][nt] = __builtin_amdgcn_mfma_f32_16x16x32_bf16(Afh[mt], Bfh[nt], acc[mt][nt], 0, 0, 0);
                    acc[mt][nt] = __builtin_amdgcn_mfma_f32_16x16x32_bf16(Afh[mt], Bfl[nt], acc[mt][nt], 0, 0, 0);
                    acc[mt][nt] = __builtin_amdgcn_mfma_f32_16x16x32_bf16(Afl[mt], Bfh[nt], acc[mt][nt], 0, 0, 0);
                }
            }
            __builtin_amdgcn_s_setprio(0);
        }
        if (s + 1 < NSTG) {
            __syncthreads();                     // all waves done reading stage s
            writeAB();                           // write-late: stage s+1 -> LDS
            __syncthreads();                     // stage s+1 visible
        }
    }

#pragma unroll
    for (int nt = 0; nt < NT; nt++) {
        int oc = nt * 16 + l16;
#pragma unroll
        for (int mt = 0; mt < MT; mt++) {
#pragma unroll
            for (int r = 0; r < 4; r++) {
                float v = acc[mt][nt][r];
                int px = pix0 + mt * 16 + quad * 4 + r;
                if (OUTMODE == 3) {
                    pf[((size_t)b * 4096 + px) * OSTRF + oc0 + oc] = v;
                } else {
                    if (ACT == 1) v = gelu_exact(v);
                    int yy = (px >> 6) + 1, xx = (px & 63) + 1;
                    int oca = oc0 + oc;
                    int och = oC0 + (oca >> 5);
                    size_t o = ((size_t)(och * 4 + b) * SLAB + yy * 66 + xx) * 32 + (oca & 31);
                    unsigned short hv, lv; split2(v, &hv, &lv);
                    oh[o] = hv; ol[o] = lv;
                }
            }
        }
    }
}

// convA: conv3 (256->64, SINGLE NT=4 role x 9 taps -> m1 DIRECT, heavy,
// dispatched first) + conv1 (grouped C->C, gelu -> h1pad).
// grid.x = 640. xcd = bx&7, j = bx>>3 in [0,80):
//   j<16: conv3 pidx=j; j>=16: jj=j-16: g=jj&3, pidx=jj>>2.
//   pair = xcd*16+pidx in [0,128) -> mb = pair&31, b = pair>>5.
__global__ __launch_bounds__(256, 1) void convA_kernel(
    const unsigned short* __restrict__ xph, const unsigned short* __restrict__ xpl,
    const unsigned short* __restrict__ w1h, const unsigned short* __restrict__ w1l,
    const float* __restrict__ off_b1,
    const unsigned short* __restrict__ w3h, const unsigned short* __restrict__ w3l,
    const float* __restrict__ mod_b1,
    unsigned short* __restrict__ h1h, unsigned short* __restrict__ h1l,
    unsigned short* __restrict__ m1h, unsigned short* __restrict__ m1l)
{
    // NT=4: A 2*2*2640 + B 2*3*64*40 = 10560 + 15360 = 25920 ush = 51,840B -> 3/CU
    __shared__ unsigned short lds[25920];
    int bx = blockIdx.x;
    int xcd = bx & 7;
    int j = bx >> 3;              // [0,80)
    if (j < 16) {
        int pair = xcd * 16 + j;
        int mb = pair & 31;
        int b = pair >> 5;
        conv_core_lds<8, 2, 4, 64, 0, 1, 1>(lds, xph, xpl, 0,
            w3h, w3l, 0, mod_b1,
            b, mb, m1h, m1l, 0, nullptr, 0);
    } else {
        int jj = j - 16;
        int g = jj & 3;
        int pair = xcd * 16 + (jj >> 2);
        int mb = pair & 31;
        int b = pair >> 5;
        conv_core_lds<2, 2, 4, 64, 0, 1, 1>(lds, xph, xpl, g * 2,
            w1h + (size_t)g * 2 * 9 * 64 * 32, w1l + (size_t)g * 2 * 9 * 64 * 32, 0,
            off_b1 + g * 64,
            b, mb, h1h, h1l, g * 2, nullptr, 0);
    }
}

// convB: conv2 (256->80pad, 2 oc-roles {48,32} x 9 taps -> P2a plain, heavy
// first) + conv4 (64->48pad, 9 taps -> P4a plain).
// grid.x = 384. xcd = bx&7, j = bx>>3 in [0,48):
//   j<32: conv2 ocr=j&1, pidx=j>>1; j>=32: conv4 pidx=j-32.
__global__ __launch_bounds__(256, 1) void convB_kernel(
    const unsigned short* __restrict__ h1h, const unsigned short* __restrict__ h1l,
    const unsigned short* __restrict__ w2h, const unsigned short* __restrict__ w2l,
    const unsigned short* __restrict__ m1h, const unsigned short* __restrict__ m1l,
    const unsigned short* __restrict__ w4h, const unsigned short* __restrict__ w4l,
    float* __restrict__ P2a, float* __restrict__ P4a)
{
    // conv2 NT=3: A 10560 + B 2*3*48*40 = 22080 ush = 44,160B -> 3/CU
    __shared__ unsigned short lds[22080];
    int bx = blockIdx.x;
    int xcd = bx & 7;
    int j = bx >> 3;              // [0,48)
    if (j < 32) {
        int ocr = j & 1;
        int pair = xcd * 16 + (j >> 1);
        int mb = pair & 31;
        int b = pair >> 5;
        if (ocr == 0) {
            conv_core_lds<8, 2, 3, 80, 80, 0, 3>(lds, h1h, h1l, 0,
                w2h, w2l, 0, nullptr, b, mb, nullptr, nullptr, 0, P2a, 0);
        } else {
            conv_core_lds<8, 2, 2, 80, 80, 0, 3>(lds, h1h, h1l, 0,
                w2h, w2l, 0, nullptr, b, mb, nullptr, nullptr, 0, P2a, 48);
        }
    } else {
        int pair = xcd * 16 + (j - 32);
        int mb = pair & 31;
        int b = pair >> 5;
        conv_core_lds<2, 2, 3, 48, 48, 0, 3>(lds, m1h, m1l, 0,
            w4h, w4l, 0, nullptr, b, mb, nullptr, nullptr, 0, P4a, 0);
    }
}

// ---------------- merged prep kernel (one dispatch) ----------------
// [0,RBLK): halo ring zero (h1, m1); [+XBLK): x -> split-bf16 chunked;
// [+WBLK): weights -> split-bf16. (No accumulator zeroing.)
#define RBLK 1040   // 4*260 ring px
#define XBLK 17424  // 4*4356
#define WBLK 1980   // 506,880 weight elements / 256
__global__ void prep_all_kernel(
    const float* __restrict__ x,
    const float* __restrict__ w1f, const float* __restrict__ w2f,
    const float* __restrict__ w3f, const float* __restrict__ w4f,
    unsigned short* __restrict__ xph, unsigned short* __restrict__ xpl,
    unsigned short* __restrict__ h1h, unsigned short* __restrict__ h1l,
    unsigned short* __restrict__ m1h, unsigned short* __restrict__ m1l,
    unsigned short* __restrict__ w1h, unsigned short* __restrict__ w1l,
    unsigned short* __restrict__ w2h, unsigned short* __restrict__ w2l,
    unsigned short* __restrict__ w3h, unsigned short* __restrict__ w3l,
    unsigned short* __restrict__ w4h, unsigned short* __restrict__ w4l)
{
    int blk = blockIdx.x;
    int t = threadIdx.x;
    if (blk < RBLK) {
        int b = blk / 260;
        int r = blk - b * 260;
        int i, j;
        if (r < 66)       { i = 0;        j = r; }
        else if (r < 132) { i = 65;       j = r - 66; }
        else if (r < 196) { i = r - 131;  j = 0; }     // rows 1..64
        else              { i = r - 195;  j = 65; }
        size_t pp = (size_t)i * 66 + j;
        int ch = t >> 5, sub = t & 31;
        size_t o = ((size_t)(ch * 4 + b) * SLAB + pp) * 32 + sub;
        h1h[o] = 0; h1l[o] = 0;
        if (t < 64) { m1h[o] = 0; m1l[o] = 0; }
        return;
    }
    blk -= RBLK;
    if (blk < XBLK) {
        int b = blk / 4356;
        int rem = blk - b * 4356;
        int i = rem / 66, j = rem - i * 66;
        float v = 0.f;
        if (i >= 1 && i <= 64 && j >= 1 && j <= 64)
            v = x[((size_t)b * 4096 + (size_t)(i - 1) * 64 + (j - 1)) * 256 + t];
        size_t o = ((size_t)((t >> 5) * 4 + b) * SLAB + rem) * 32 + (t & 31);
        unsigned short h, l; split2(v, &h, &l);
        xph[o] = h; xpl[o] = l;
        return;
    }
    blk -= XBLK;
    {
        const int N1 = 147456, N2 = 184320, N3 = 147456, N4 = 27648;
        int idx = blk * 256 + t;
        const float* w; unsigned short *outh, *outl;
        int ocpad, oc_real, ic, base;
        if (idx < N1)                { w = w1f; outh = w1h; outl = w1l; ocpad = 64; oc_real = 64; ic = 64;  base = 0; }
        else if (idx < N1 + N2)      { w = w2f; outh = w2h; outl = w2l; ocpad = 80; oc_real = 72; ic = 256; base = N1; }
        else if (idx < N1 + N2 + N3) { w = w3f; outh = w3h; outl = w3l; ocpad = 64; oc_real = 64; ic = 256; base = N1 + N2; }
        else                         { w = w4f; outh = w4h; outl = w4l; ocpad = 48; oc_real = 36; ic = 64;  base = N1 + N2 + N3; }
        int lidx = idx - base;
        // lidx -> [g][ch][tap][ocp][ici]
        int ici = lidx & 31;
        int t1 = lidx >> 5;
        int ocp = t1 % ocpad;
        int t2 = t1 / ocpad;
        int tap = t2 % 9;
        int t3 = t2 / 9;
        int nch = ic >> 5;
        int ch = t3 % nch;
        int g = t3 / nch;
        float v = 0.f;
        if (ocp < oc_real) {
            int oc = g * oc_real + ocp;
            int icx = ch * 32 + ici;
            v = w[((size_t)oc * ic + icx) * 9 + tap];
        }
        unsigned short h, l; split2(v, &h, &l);
        outh[lidx] = h; outl[lidx] = l;
    }
}

// ---------------- deformable sampling (exact fp32, finalizeB fused) ----------------
// 4 points per wave, 16 lanes per point, float4 gathers (4 channels/lane).
// XCD swizzle: each XCD gets 512 contiguous blocks (L2-resident x window).
__global__ __launch_bounds__(256) void deform_sample(
    const float* __restrict__ x,
    const float* __restrict__ P2a, const float* __restrict__ P4a,
    const float* __restrict__ b2, const float* __restrict__ b4,
    float* __restrict__ out)
{
    int bid = (int)((blockIdx.x & 7u) * 512u + (blockIdx.x >> 3));   // XCD slab swizzle
    int wid = (int)(((unsigned)bid * 256u + threadIdx.x) >> 6);      // 0..16383
    int lane = (int)(threadIdx.x & 63u);
    int sub = lane >> 4;         // 0..3: which point
    int li = lane & 15;

    int b = wid >> 12;           // 4096 waves per batch
    int rem = wid & 4095;
    int g = rem >> 10;
    int hw = ((rem & 1023) << 2) + sub;
    int hy = hw >> 6;
    int wx = hw & 63;

    // lanes li<9 of each subwave: offsets (P2a+b2) and modulation sigmoid(P4a+b4)
    float fx = 0.f, fy = 0.f, fm = 0.f;
    if (li < 9) {
        size_t p = (size_t)(b << 12) + hw;
        int c2 = g * 18 + li;
        fx = P2a[p * 80 + c2] + b2[c2];
        fy = P2a[p * 80 + 9 + c2] + b2[9 + c2];
        int c4 = g * 9 + li;
        float mv = P4a[p * 48 + c4] + b4[c4];
        fm = 1.0f / (1.0f + expf(-mv));
    }
    float px = fminf(fmaxf((float)wx + (float)(li % 3 - 1) + fx, 0.f), 63.f);
    float py = fminf(fmaxf((float)hy + (float)(li / 3 - 1) + fy, 0.f), 63.f);
    float x0f = floorf(px), y0f = floorf(py);
    float wxf = px - x0f, wyf = py - y0f;
    int x0 = (int)x0f, y0 = (int)y0f;
    int x1 = min(x0 + 1, 63), y1 = min(y0 + 1, 63);

    // lane li gathers channels g*64 + li*4 .. +3 as float4
    const float4* xb = (const float4*)(x + ((size_t)(b << 12)) * 256 + g * 64 + li * 4);
    float4 acc = make_float4(0.f, 0.f, 0.f, 0.f);
    int sb = sub << 4;
#pragma unroll
    for (int q = 0; q < 9; q++) {
        int src = sb + q;
        int   qx0 = __shfl(x0, src);
        int   qx1 = __shfl(x1, src);
        int   qy0 = __shfl(y0, src);
        int   qy1 = __shfl(y1, src);
        float qwx = __shfl(wxf, src);
        float qwy = __shfl(wyf, src);
        float qm  = __shfl(fm, src);
        float4 v00 = xb[(size_t)(qy0 * 64 + qx0) * 64];
        float4 v01 = xb[(size_t)(qy0 * 64 + qx1) * 64];
        float4 v10 = xb[(size_t)(qy1 * 64 + qx0) * 64];
        float4 v11 = xb[(size_t)(qy1 * 64 + qx1) * 64];
        float w00 = (1.f - qwx) * (1.f - qwy);
        float w01 = qwx * (1.f - qwy);
        float w10 = (1.f - qwx) * qwy;
        float w11 = qwx * qwy;
        acc.x += qm * (v00.x * w00 + v01.x * w01 + v10.x * w10 + v11.x * w11);
        acc.y += qm * (v00.y * w00 + v01.y * w01 + v10.y * w10 + v11.y * w11);
        acc.z += qm * (v00.z * w00 + v01.z * w01 + v10.z * w10 + v11.z * w11);
        acc.w += qm * (v00.w * w00 + v01.w * w01 + v10.w * w10 + v11.w * w11);
    }
    const float s = 1.f / 9.f;
    acc.x *= s; acc.y *= s; acc.z *= s; acc.w *= s;
    float4* ob = (float4*)(out + ((size_t)(b << 12) + hw) * 256 + g * 64 + li * 4);
    *ob = acc;
}

extern "C" void kernel_launch(void* const* d_in, const int* in_sizes, int n_in,
                              void* d_out, int out_size, void* d_ws, size_t ws_size,
                              hipStream_t stream)
{
    const float* x      = (const float*)d_in[0];
    const float* off_w1 = (const float*)d_in[1];
    const float* off_b1 = (const float*)d_in[2];
    const float* off_w2 = (const float*)d_in[3];
    const float* off_b2 = (const float*)d_in[4];
    const float* mod_w1 = (const float*)d_in[5];
    const float* mod_b1 = (const float*)d_in[6];
    const float* mod_w2 = (const float*)d_in[7];
    const float* mod_b2 = (const float*)d_in[8];

    // ws layout (ushort units; split hi/lo arrays, 64B px units, SLAB-padded)
    const size_t XP = 8u * 4u * SLAB * 32u;      // 8 chunks x 4 b x SLAB x 32
    const size_t MP = 2u * 4u * SLAB * 32u;      // 2 chunks
    const size_t W1 = 4u * 2u * 9u * 64u * 32u;  // 147,456
    const size_t W2 = 8u * 9u * 80u * 32u;       // 184,320
    const size_t W3 = 8u * 9u * 64u * 32u;       // 147,456
    const size_t W4 = 2u * 9u * 48u * 32u;       // 27,648

    unsigned short* ws = (unsigned short*)d_ws;
    size_t o = 0;
    unsigned short* xph = ws + o; o += XP + AGAP;
    unsigned short* xpl = ws + o; o += XP + AGAP;
    unsigned short* h1h = ws + o; o += XP + AGAP;
    unsigned short* h1l = ws + o; o += XP + AGAP;
    unsigned short* m1h = ws + o; o += MP + AGAP;
    unsigned short* m1l = ws + o; o += MP + AGAP;
    unsigned short* w1h = ws + o; o += W1 + AGAP;
    unsigned short* w1l = ws + o; o += W1 + AGAP;
    unsigned short* w2h = ws + o; o += W2 + AGAP;
    unsigned short* w2l = ws + o; o += W2 + AGAP;
    unsigned short* w3h = ws + o; o += W3 + AGAP;
    unsigned short* w3l = ws + o; o += W3 + AGAP;
    unsigned short* w4h = ws + o; o += W4 + AGAP;
    unsigned short* w4l = ws + o; o += W4 + AGAP;
    o += o & 1;  // align to 4B for float section
    // fp32 outputs: P2a/P4a fully plain-written by convB (no init needed)
    float* fbase = (float*)(ws + o);
    float* P2a = fbase;                              // [4*4096][80]
    float* P4a = P2a + (size_t)4 * 4096 * 80;        // [4*4096][48]
    const size_t ACC_FLOATS = (size_t)4 * 4096 * (80 + 48);
    size_t need_bytes = o * 2 + ACC_FLOATS * 4;      // ~51 MB (ws ~268 MB)
    if (ws_size < need_bytes) return;  // deterministic guard

    prep_all_kernel<<<RBLK + XBLK + WBLK, 256, 0, stream>>>(
        x, off_w1, off_w2, mod_w1, mod_w2,
        xph, xpl, h1h, h1l, m1h, m1l,
        w1h, w1l, w2h, w2l, w3h, w3l, w4h, w4l);

    convA_kernel<<<dim3(640, 1, 1), 256, 0, stream>>>(xph, xpl, w1h, w1l, off_b1,
                                                      w3h, w3l, mod_b1,
                                                      h1h, h1l, m1h, m1l);
    convB_kernel<<<dim3(384, 1, 1), 256, 0, stream>>>(h1h, h1l, w2h, w2l,
                                                      m1h, m1l, w4h, w4l, P2a, P4a);
    deform_sample<<<4096, 256, 0, stream>>>(x, P2a, P4a, off_b2, mod_b2, (float*)d_out);
}

// Round 13
// 181.978 us; speedup vs baseline: 1.0679x; 1.0679x over previous
//
#include <hip/hip_runtime.h>
#include <math.h>

// B=4, C=256, H=W=64, G=4, Cg=64, P=9. x [B,HW,C] is NHWC already.
// Convs via implicit-GEMM MFMA (bf16 2-term split: hi*hi + hi*lo + lo*hi).
// Chunked SPLIT-ARRAY layout: activations [ch][b][SLAB px][32] hi/lo arrays.
// R19 (BEST, 182.3us): oc-split conv3 -> m1 direct, no atomics/finalize.
// R20 REGRESSED (194.3): single-role conv3 = 128 heavy blocks for 256 CUs ->
//   half the CUs carry the 24-stage tail. Balance > staging traffic.
// R21: revert to R19 exactly (one heavy block per CU) + deform_sample
//   weight-folding (qm folded into bilinear weights once per tap; channel
//   accum becomes pure fma chains, ~25% fewer VALU ops).

#define SLAB 4369           // padded px per (ch,b) slab (4356 used + 13 pad)
#define AGAP 1056           // ushorts between arrays
#define APXS 40             // LDS padded px/oc stride in ushorts (80B)
#define AROW (66*APXS)      // 2640 ushorts per LDS A row

typedef __attribute__((ext_vector_type(8))) short short8;
typedef __attribute__((ext_vector_type(4))) float floatx4;

__device__ __forceinline__ unsigned short f2bf(float f) {
    unsigned u = __float_as_uint(f);
    u = (u + 0x7FFFu + ((u >> 16) & 1u)) >> 16;
    return (unsigned short)u;
}
__device__ __forceinline__ float bf2f(unsigned short h) {
    return __uint_as_float(((unsigned)h) << 16);
}
__device__ __forceinline__ void split2(float v, unsigned short* hi, unsigned short* lo) {
    unsigned short h = f2bf(v);
    *hi = h;
    *lo = f2bf(v - bf2f(h));
}
__device__ __forceinline__ float gelu_exact(float v) {
    return 0.5f * v * (1.0f + erff(v * 0.70710678118654752f));
}

// ---------------- LDS-staged MFMA implicit-GEMM conv core (3-tap stages) -----
// Global activations: [ch][b][SLAB px][32] ushort (hi/lo). px = y*66+x, padded.
// Global weights: [ch][tap][OCW][32] ushort (hi/lo); role reads cols
// oc0..oc0+NT*16 of each tap row (strided per-tap staging).
// Block = 4 waves, MT=2: wave = 32 px (half row); block = 128 px = 2 rows.
// Stage = one (ch, kh): A = 2 rows at y0+kh; B = 3 taps x NT*16 oc.
// NSTG = NC*3 stages. Per stage: [issue s+1] -> 3x(ds_read + MFMA) -> sync ->
// [write s+1] -> sync.
// A frag: m=l16 -> pixel, k=quad*8+j -> ic. B frag: n=l16 -> oc.
// C/D: col(oc)=lane&15, row(pixel)=quad*4+reg.
// ACT: 0 none, 1 gelu. OUTMODE: 1 split-bf16 out (bias+act) at column oc0+oc;
// 3 fp32 plain store, row stride OSTRF, column oc0+oc.
template<int NC, int MT, int NT, int OCW, int OSTRF, int ACT, int OUTMODE>
__device__ __forceinline__ void conv_core_lds(
    unsigned short* lds,
    const unsigned short* __restrict__ ah, const unsigned short* __restrict__ al,
    int aC0,
    const unsigned short* __restrict__ wh, const unsigned short* __restrict__ wl,
    int wC0,
    const float* __restrict__ bias,
    int b, int mblock,
    unsigned short* __restrict__ oh, unsigned short* __restrict__ ol,
    int oC0,
    float* __restrict__ pf,
    int oc0)
{
    const int NSTG = NC * 3;
    const int AHALF_ = MT * AROW;
    const int AU = MT * 66 * 4;          // 16B units per A half
    const int KA = (AU + 255) / 256;
    const int BHALF_ = 3 * NT * 16 * APXS;
    const int UB1 = NT * 64;             // 16B units per tap per half
    const int BU = 3 * UB1;
    const int KB = (BU + 255) / 256;

    unsigned short* Ahl = lds;
    unsigned short* All = lds + AHALF_;
    unsigned short* Bhl = lds + 2 * AHALF_;
    unsigned short* Bll = Bhl + BHALF_;

    int tid = (int)threadIdx.x;
    int wave = tid >> 6;
    int lane = tid & 63;
    int quad = lane >> 4;
    int l16 = lane & 15;

    int pix0 = (mblock * 4 + wave) * (MT * 16);
    int y0 = mblock * MT;                       // block's first image row
    int lr = wave >> 1;                         // wave's local row (MT=2)
    int xb_ = (wave & 1) * 32;

    floatx4 acc[MT][NT];
#pragma unroll
    for (int nt = 0; nt < NT; nt++) {
        float bv = (OUTMODE == 1) ? bias[nt * 16 + l16] : 0.f;
#pragma unroll
        for (int mt = 0; mt < MT; mt++) { floatx4 v = {bv, bv, bv, bv}; acc[mt][nt] = v; }
    }

    short8 ARh[KA], ARl[KA], BRh[KB], BRl[KB];

    auto issueAB = [&](int s) {
        int ch = s / 3;
        int kh = s % 3;
        size_t ga = ((size_t)((aC0 + ch) * 4 + b) * SLAB + (size_t)(y0 + kh) * 66) * 32;
#pragma unroll
        for (int k = 0; k < KA; k++) {
            int u = k * 256 + tid;
            if (u < AU) {
                ARh[k] = *(const short8*)(ah + ga + (size_t)u * 8);
                ARl[k] = *(const short8*)(al + ga + (size_t)u * 8);
            }
        }
        size_t gb = (((size_t)(wC0 + ch) * 9 + kh * 3) * OCW + oc0) * 32;
#pragma unroll
        for (int k = 0; k < KB; k++) {
            int u = k * 256 + tid;
            if (u < BU) {
                int tp = u / UB1;
                int r = u - tp * UB1;
                size_t src = gb + (size_t)tp * OCW * 32 + (size_t)r * 8;
                BRh[k] = *(const short8*)(wh + src);
                BRl[k] = *(const short8*)(wl + src);
            }
        }
    };
    auto writeAB = [&]() {
#pragma unroll
        for (int k = 0; k < KA; k++) {
            int u = k * 256 + tid;
            if (u < AU) {
                int px = u >> 2, j = u & 3;
                int row = px / 66, col = px - row * 66;
                int dst = row * AROW + col * APXS + j * 8;
                *(short8*)(Ahl + dst) = ARh[k];
                *(short8*)(All + dst) = ARl[k];
            }
        }
#pragma unroll
        for (int k = 0; k < KB; k++) {
            int u = k * 256 + tid;
            if (u < BU) {
                int tp = u / UB1;
                int r = u - tp * UB1;
                int dst = tp * (NT * 16 * APXS) + (r >> 2) * APXS + (r & 3) * 8;
                *(short8*)(Bhl + dst) = BRh[k];
                *(short8*)(Bll + dst) = BRl[k];
            }
        }
    };

    issueAB(0);
    writeAB();
    __syncthreads();

#pragma unroll 1
    for (int s = 0; s < NSTG; s++) {
        if (s + 1 < NSTG) {
            issueAB(s + 1);                      // issue-early: in flight under MFMA
            __builtin_amdgcn_sched_barrier(0);
        }
#pragma unroll
        for (int kw = 0; kw < 3; kw++) {
            short8 Afh[MT], Afl[MT], Bfh[NT], Bfl[NT];
#pragma unroll
            for (int mt = 0; mt < MT; mt++) {
                int aoff = lr * AROW + (xb_ + kw + l16 + mt * 16) * APXS + quad * 8;
                Afh[mt] = *(const short8*)(Ahl + aoff);
                Afl[mt] = *(const short8*)(All + aoff);
            }
#pragma unroll
            for (int nt = 0; nt < NT; nt++) {
                int boff = kw * (NT * 16 * APXS) + (nt * 16 + l16) * APXS + quad * 8;
                Bfh[nt] = *(const short8*)(Bhl + boff);
                Bfl[nt] = *(const short8*)(Bll + boff);
            }
            __builtin_amdgcn_s_setprio(1);
#pragma unroll
            for (int nt = 0; nt < NT; nt++) {
#pragma unroll
                for (int mt = 0; mt < MT; mt++) {
                    acc[mt][nt] = __builtin_amdgcn_mfma_f32_16x16x32_bf16(Afh[mt], Bfh[nt], acc[mt][nt], 0, 0, 0);
                    acc[mt][nt] = __builtin_amdgcn_mfma_f32_16x16x32_bf16(Afh[mt], Bfl[nt], acc[mt][nt], 0, 0, 0);
                    acc[mt][nt] = __builtin_amdgcn_mfma_f32_16x16x32_bf16(Afl[mt], Bfh[nt], acc[mt][nt], 0, 0, 0);
                }
            }
            __builtin_amdgcn_s_setprio(0);
        }
        if (s + 1 < NSTG) {
            __syncthreads();                     // all waves done reading stage s
            writeAB();                           // write-late: stage s+1 -> LDS
            __syncthreads();                     // stage s+1 visible
        }
    }

#pragma unroll
    for (int nt = 0; nt < NT; nt++) {
        int oc = nt * 16 + l16;
#pragma unroll
        for (int mt = 0; mt < MT; mt++) {
#pragma unroll
            for (int r = 0; r < 4; r++) {
                float v = acc[mt][nt][r];
                int px = pix0 + mt * 16 + quad * 4 + r;
                if (OUTMODE == 3) {
                    pf[((size_t)b * 4096 + px) * OSTRF + oc0 + oc] = v;
                } else {
                    if (ACT == 1) v = gelu_exact(v);
                    int yy = (px >> 6) + 1, xx = (px & 63) + 1;
                    int oca = oc0 + oc;
                    int och = oC0 + (oca >> 5);
                    size_t o = ((size_t)(och * 4 + b) * SLAB + yy * 66 + xx) * 32 + (oca & 31);
                    unsigned short hv, lv; split2(v, &hv, &lv);
                    oh[o] = hv; ol[o] = lv;
                }
            }
        }
    }
}

// convA: conv3 (256->64, 2 oc-roles x 9 taps -> m1 DIRECT, heavy, dispatched
// first) + conv1 (grouped C->C, gelu -> h1pad).  [R19 config: one heavy
// block per CU]
// grid.x = 768. xcd = bx&7, j = bx>>3 in [0,96):
//   j<32: conv3 ocr=j&1, pidx=j>>1; j>=32: jj=j-32: g=jj&3, pidx=jj>>2.
//   pair = xcd*16+pidx in [0,128) -> mb = pair&31, b = pair>>5.
__global__ __launch_bounds__(256, 1) void convA_kernel(
    const unsigned short* __restrict__ xph, const unsigned short* __restrict__ xpl,
    const unsigned short* __restrict__ w1h, const unsigned short* __restrict__ w1l,
    const float* __restrict__ off_b1,
    const unsigned short* __restrict__ w3h, const unsigned short* __restrict__ w3l,
    const float* __restrict__ mod_b1,
    unsigned short* __restrict__ h1h, unsigned short* __restrict__ h1l,
    unsigned short* __restrict__ m1h, unsigned short* __restrict__ m1l)
{
    // conv1: A 2*2*2640 + B 2*3*64*40 = 25920 ush = 51,840B -> 3/CU
    __shared__ unsigned short lds[25920];
    int bx = blockIdx.x;
    int xcd = bx & 7;
    int j = bx >> 3;              // [0,96)
    if (j < 32) {
        int ocr = j & 1;
        int pair = xcd * 16 + (j >> 1);
        int mb = pair & 31;
        int b = pair >> 5;
        conv_core_lds<8, 2, 2, 64, 0, 1, 1>(lds, xph, xpl, 0,
            w3h, w3l, 0, mod_b1 + ocr * 32,
            b, mb, m1h, m1l, 0, nullptr, ocr * 32);
    } else {
        int jj = j - 32;
        int g = jj & 3;
        int pair = xcd * 16 + (jj >> 2);
        int mb = pair & 31;
        int b = pair >> 5;
        conv_core_lds<2, 2, 4, 64, 0, 1, 1>(lds, xph, xpl, g * 2,
            w1h + (size_t)g * 2 * 9 * 64 * 32, w1l + (size_t)g * 2 * 9 * 64 * 32, 0,
            off_b1 + g * 64,
            b, mb, h1h, h1l, g * 2, nullptr, 0);
    }
}

// convB: conv2 (256->80pad, 2 oc-roles {48,32} x 9 taps -> P2a plain, heavy
// first) + conv4 (64->48pad, 9 taps -> P4a plain).
// grid.x = 384. xcd = bx&7, j = bx>>3 in [0,48):
//   j<32: conv2 ocr=j&1, pidx=j>>1; j>=32: conv4 pidx=j-32.
__global__ __launch_bounds__(256, 1) void convB_kernel(
    const unsigned short* __restrict__ h1h, const unsigned short* __restrict__ h1l,
    const unsigned short* __restrict__ w2h, const unsigned short* __restrict__ w2l,
    const unsigned short* __restrict__ m1h, const unsigned short* __restrict__ m1l,
    const unsigned short* __restrict__ w4h, const unsigned short* __restrict__ w4l,
    float* __restrict__ P2a, float* __restrict__ P4a)
{
    // conv2 NT=3: A 10560 + B 2*3*48*40 = 22080 ush = 44,160B -> 3/CU
    __shared__ unsigned short lds[22080];
    int bx = blockIdx.x;
    int xcd = bx & 7;
    int j = bx >> 3;              // [0,48)
    if (j < 32) {
        int ocr = j & 1;
        int pair = xcd * 16 + (j >> 1);
        int mb = pair & 31;
        int b = pair >> 5;
        if (ocr == 0) {
            conv_core_lds<8, 2, 3, 80, 80, 0, 3>(lds, h1h, h1l, 0,
                w2h, w2l, 0, nullptr, b, mb, nullptr, nullptr, 0, P2a, 0);
        } else {
            conv_core_lds<8, 2, 2, 80, 80, 0, 3>(lds, h1h, h1l, 0,
                w2h, w2l, 0, nullptr, b, mb, nullptr, nullptr, 0, P2a, 48);
        }
    } else {
        int pair = xcd * 16 + (j - 32);
        int mb = pair & 31;
        int b = pair >> 5;
        conv_core_lds<2, 2, 3, 48, 48, 0, 3>(lds, m1h, m1l, 0,
            w4h, w4l, 0, nullptr, b, mb, nullptr, nullptr, 0, P4a, 0);
    }
}

// ---------------- merged prep kernel (one dispatch) ----------------
// [0,RBLK): halo ring zero (h1, m1); [+XBLK): x -> split-bf16 chunked;
// [+WBLK): weights -> split-bf16. (No accumulator zeroing.)
#define RBLK 1040   // 4*260 ring px
#define XBLK 17424  // 4*4356
#define WBLK 1980   // 506,880 weight elements / 256
__global__ void prep_all_kernel(
    const float* __restrict__ x,
    const float* __restrict__ w1f, const float* __restrict__ w2f,
    const float* __restrict__ w3f, const float* __restrict__ w4f,
    unsigned short* __restrict__ xph, unsigned short* __restrict__ xpl,
    unsigned short* __restrict__ h1h, unsigned short* __restrict__ h1l,
    unsigned short* __restrict__ m1h, unsigned short* __restrict__ m1l,
    unsigned short* __restrict__ w1h, unsigned short* __restrict__ w1l,
    unsigned short* __restrict__ w2h, unsigned short* __restrict__ w2l,
    unsigned short* __restrict__ w3h, unsigned short* __restrict__ w3l,
    unsigned short* __restrict__ w4h, unsigned short* __restrict__ w4l)
{
    int blk = blockIdx.x;
    int t = threadIdx.x;
    if (blk < RBLK) {
        int b = blk / 260;
        int r = blk - b * 260;
        int i, j;
        if (r < 66)       { i = 0;        j = r; }
        else if (r < 132) { i = 65;       j = r - 66; }
        else if (r < 196) { i = r - 131;  j = 0; }     // rows 1..64
        else              { i = r - 195;  j = 65; }
        size_t pp = (size_t)i * 66 + j;
        int ch = t >> 5, sub = t & 31;
        size_t o = ((size_t)(ch * 4 + b) * SLAB + pp) * 32 + sub;
        h1h[o] = 0; h1l[o] = 0;
        if (t < 64) { m1h[o] = 0; m1l[o] = 0; }
        return;
    }
    blk -= RBLK;
    if (blk < XBLK) {
        int b = blk / 4356;
        int rem = blk - b * 4356;
        int i = rem / 66, j = rem - i * 66;
        float v = 0.f;
        if (i >= 1 && i <= 64 && j >= 1 && j <= 64)
            v = x[((size_t)b * 4096 + (size_t)(i - 1) * 64 + (j - 1)) * 256 + t];
        size_t o = ((size_t)((t >> 5) * 4 + b) * SLAB + rem) * 32 + (t & 31);
        unsigned short h, l; split2(v, &h, &l);
        xph[o] = h; xpl[o] = l;
        return;
    }
    blk -= XBLK;
    {
        const int N1 = 147456, N2 = 184320, N3 = 147456, N4 = 27648;
        int idx = blk * 256 + t;
        const float* w; unsigned short *outh, *outl;
        int ocpad, oc_real, ic, base;
        if (idx < N1)                { w = w1f; outh = w1h; outl = w1l; ocpad = 64; oc_real = 64; ic = 64;  base = 0; }
        else if (idx < N1 + N2)      { w = w2f; outh = w2h; outl = w2l; ocpad = 80; oc_real = 72; ic = 256; base = N1; }
        else if (idx < N1 + N2 + N3) { w = w3f; outh = w3h; outl = w3l; ocpad = 64; oc_real = 64; ic = 256; base = N1 + N2; }
        else                         { w = w4f; outh = w4h; outl = w4l; ocpad = 48; oc_real = 36; ic = 64;  base = N1 + N2 + N3; }
        int lidx = idx - base;
        // lidx -> [g][ch][tap][ocp][ici]
        int ici = lidx & 31;
        int t1 = lidx >> 5;
        int ocp = t1 % ocpad;
        int t2 = t1 / ocpad;
        int tap = t2 % 9;
        int t3 = t2 / 9;
        int nch = ic >> 5;
        int ch = t3 % nch;
        int g = t3 / nch;
        float v = 0.f;
        if (ocp < oc_real) {
            int oc = g * oc_real + ocp;
            int icx = ch * 32 + ici;
            v = w[((size_t)oc * ic + icx) * 9 + tap];
        }
        unsigned short h, l; split2(v, &h, &l);
        outh[lidx] = h; outl[lidx] = l;
    }
}

// ---------------- deformable sampling (exact fp32, finalizeB fused) ----------------
// 4 points per wave, 16 lanes per point, float4 gathers (4 channels/lane).
// XCD swizzle: each XCD gets 512 contiguous blocks (L2-resident x window).
// R21: qm folded into bilinear weights once per tap -> channel accum = pure
// 4-deep fma chains (~25% fewer VALU ops).
__global__ __launch_bounds__(256) void deform_sample(
    const float* __restrict__ x,
    const float* __restrict__ P2a, const float* __restrict__ P4a,
    const float* __restrict__ b2, const float* __restrict__ b4,
    float* __restrict__ out)
{
    int bid = (int)((blockIdx.x & 7u) * 512u + (blockIdx.x >> 3));   // XCD slab swizzle
    int wid = (int)(((unsigned)bid * 256u + threadIdx.x) >> 6);      // 0..16383
    int lane = (int)(threadIdx.x & 63u);
    int sub = lane >> 4;         // 0..3: which point
    int li = lane & 15;

    int b = wid >> 12;           // 4096 waves per batch
    int rem = wid & 4095;
    int g = rem >> 10;
    int hw = ((rem & 1023) << 2) + sub;
    int hy = hw >> 6;
    int wx = hw & 63;

    // lanes li<9 of each subwave: offsets (P2a+b2) and modulation sigmoid(P4a+b4)
    float fx = 0.f, fy = 0.f, fm = 0.f;
    if (li < 9) {
        size_t p = (size_t)(b << 12) + hw;
        int c2 = g * 18 + li;
        fx = P2a[p * 80 + c2] + b2[c2];
        fy = P2a[p * 80 + 9 + c2] + b2[9 + c2];
        int c4 = g * 9 + li;
        float mv = P4a[p * 48 + c4] + b4[c4];
        fm = 1.0f / (1.0f + expf(-mv));
    }
    float px = fminf(fmaxf((float)wx + (float)(li % 3 - 1) + fx, 0.f), 63.f);
    float py = fminf(fmaxf((float)hy + (float)(li / 3 - 1) + fy, 0.f), 63.f);
    float x0f = floorf(px), y0f = floorf(py);
    float wxf = px - x0f, wyf = py - y0f;
    int x0 = (int)x0f, y0 = (int)y0f;
    int x1 = min(x0 + 1, 63), y1 = min(y0 + 1, 63);

    // lane li gathers channels g*64 + li*4 .. +3 as float4
    const float4* xb = (const float4*)(x + ((size_t)(b << 12)) * 256 + g * 64 + li * 4);
    float4 acc = make_float4(0.f, 0.f, 0.f, 0.f);
    int sb = sub << 4;
#pragma unroll
    for (int q = 0; q < 9; q++) {
        int src = sb + q;
        int   qx0 = __shfl(x0, src);
        int   qx1 = __shfl(x1, src);
        int   qy0 = __shfl(y0, src);
        int   qy1 = __shfl(y1, src);
        float qwx = __shfl(wxf, src);
        float qwy = __shfl(wyf, src);
        float qm  = __shfl(fm, src);
        float4 v00 = xb[(size_t)(qy0 * 64 + qx0) * 64];
        float4 v01 = xb[(size_t)(qy0 * 64 + qx1) * 64];
        float4 v10 = xb[(size_t)(qy1 * 64 + qx0) * 64];
        float4 v11 = xb[(size_t)(qy1 * 64 + qx1) * 64];
        // fold modulation into the bilinear weights (4 muls), then pure fma
        float w11 = qwx * qwy * qm;
        float w01 = qwx * qm - w11;
        float w10 = qwy * qm - w11;
        float w00 = qm - w01 - w10 - w11;
        acc.x = fmaf(v00.x, w00, fmaf(v01.x, w01, fmaf(v10.x, w10, fmaf(v11.x, w11, acc.x))));
        acc.y = fmaf(v00.y, w00, fmaf(v01.y, w01, fmaf(v10.y, w10, fmaf(v11.y, w11, acc.y))));
        acc.z = fmaf(v00.z, w00, fmaf(v01.z, w01, fmaf(v10.z, w10, fmaf(v11.z, w11, acc.z))));
        acc.w = fmaf(v00.w, w00, fmaf(v01.w, w01, fmaf(v10.w, w10, fmaf(v11.w, w11, acc.w))));
    }
    const float s = 1.f / 9.f;
    acc.x *= s; acc.y *= s; acc.z *= s; acc.w *= s;
    float4* ob = (float4*)(out + ((size_t)(b << 12) + hw) * 256 + g * 64 + li * 4);
    *ob = acc;
}

extern "C" void kernel_launch(void* const* d_in, const int* in_sizes, int n_in,
                              void* d_out, int out_size, void* d_ws, size_t ws_size,
                              hipStream_t stream)
{
    const float* x      = (const float*)d_in[0];
    const float* off_w1 = (const float*)d_in[1];
    const float* off_b1 = (const float*)d_in[2];
    const float* off_w2 = (const float*)d_in[3];
    const float* off_b2 = (const float*)d_in[4];
    const float* mod_w1 = (const float*)d_in[5];
    const float* mod_b1 = (const float*)d_in[6];
    const float* mod_w2 = (const float*)d_in[7];
    const float* mod_b2 = (const float*)d_in[8];

    // ws layout (ushort units; split hi/lo arrays, 64B px units, SLAB-padded)
    const size_t XP = 8u * 4u * SLAB * 32u;      // 8 chunks x 4 b x SLAB x 32
    const size_t MP = 2u * 4u * SLAB * 32u;      // 2 chunks
    const size_t W1 = 4u * 2u * 9u * 64u * 32u;  // 147,456
    const size_t W2 = 8u * 9u * 80u * 32u;       // 184,320
    const size_t W3 = 8u * 9u * 64u * 32u;       // 147,456
    const size_t W4 = 2u * 9u * 48u * 32u;       // 27,648

    unsigned short* ws = (unsigned short*)d_ws;
    size_t o = 0;
    unsigned short* xph = ws + o; o += XP + AGAP;
    unsigned short* xpl = ws + o; o += XP + AGAP;
    unsigned short* h1h = ws + o; o += XP + AGAP;
    unsigned short* h1l = ws + o; o += XP + AGAP;
    unsigned short* m1h = ws + o; o += MP + AGAP;
    unsigned short* m1l = ws + o; o += MP + AGAP;
    unsigned short* w1h = ws + o; o += W1 + AGAP;
    unsigned short* w1l = ws + o; o += W1 + AGAP;
    unsigned short* w2h = ws + o; o += W2 + AGAP;
    unsigned short* w2l = ws + o; o += W2 + AGAP;
    unsigned short* w3h = ws + o; o += W3 + AGAP;
    unsigned short* w3l = ws + o; o += W3 + AGAP;
    unsigned short* w4h = ws + o; o += W4 + AGAP;
    unsigned short* w4l = ws + o; o += W4 + AGAP;
    o += o & 1;  // align to 4B for float section
    // fp32 outputs: P2a/P4a fully plain-written by convB (no init needed)
    float* fbase = (float*)(ws + o);
    float* P2a = fbase;                              // [4*4096][80]
    float* P4a = P2a + (size_t)4 * 4096 * 80;        // [4*4096][48]
    const size_t ACC_FLOATS = (size_t)4 * 4096 * (80 + 48);
    size_t need_bytes = o * 2 + ACC_FLOATS * 4;      // ~51 MB (ws ~268 MB)
    if (ws_size < need_bytes) return;  // deterministic guard

    prep_all_kernel<<<RBLK + XBLK + WBLK, 256, 0, stream>>>(
        x, off_w1, off_w2, mod_w1, mod_w2,
        xph, xpl, h1h, h1l, m1h, m1l,
        w1h, w1l, w2h, w2l, w3h, w3l, w4h, w4l);

    convA_kernel<<<dim3(768, 1, 1), 256, 0, stream>>>(xph, xpl, w1h, w1l, off_b1,
                                                      w3h, w3l, mod_b1,
                                                      h1h, h1l, m1h, m1l);
    convB_kernel<<<dim3(384, 1, 1), 256, 0, stream>>>(h1h, h1l, w2h, w2l,
                                                      m1h, m1l, w4h, w4l, P2a, P4a);
    deform_sample<<<4096, 256, 0, stream>>>(x, P2a, P4a, off_b2, mod_b2, (float*)d_out);
}